// Round 8
// baseline (306.477 us; speedup 1.0000x reference)
//
#include <hip/hip_runtime.h>

#define EPG 56
#define ROWS 56      // rows per pair (2 graphs)
#define EDG 112      // edges per pair
#define CH 128
#define LDW 136      // Hs leading dim (bf16 elems), +8 pad

// CSR blob layout per pair (int32 words): dinv f32 @0(56), rs @64(57),
// src @128(112), nrm f32 @240(112). Stride 384 words = 1536 B.
#define CSR_WORDS 384

typedef float f32x4 __attribute__((ext_vector_type(4)));
typedef __bf16 bf16x8 __attribute__((ext_vector_type(8)));
typedef unsigned short u16;
typedef u16 u16x8 __attribute__((ext_vector_type(8)));
typedef u16 u16x4 __attribute__((ext_vector_type(4)));

__device__ __forceinline__ u16 f2bf(float f){
  union { float f; unsigned u; } v; v.f = f;
  unsigned r = (v.u + 0x7fffu + ((v.u >> 16) & 1u)) >> 16;  // RNE
  return (u16)r;
}
__device__ __forceinline__ float bf2f(u16 h){
  union { unsigned u; float f; } v; v.u = ((unsigned)h) << 16;
  return v.f;
}

// Pack W (f32 [128][128], row k, col c) into MFMA B-fragment order, bf16:
// wp[((ct*4+ks)*64 + l)*8 + j] = bf16( W[(l>>4)*8 + ks*32 + j][ct*16 + (l&15)] )
__global__ void pack_w(const float* __restrict__ W, u16* __restrict__ wp){
  int d = blockIdx.x * 256 + threadIdx.x;           // 0..16383
  int j  = d & 7;
  int l  = (d >> 3) & 63;
  int ks = (d >> 9) & 3;
  int ct = d >> 11;
  int k = ((l >> 4) << 3) + (ks << 5) + j;
  int c = (ct << 4) + (l & 15);
  wp[d] = f2bf(W[k * CH + c]);
}

// Pre-pass: per-pair degree/norm/CSR into d_ws.
__global__ __launch_bounds__(128)
void build_csr(const int* __restrict__ ei, const float* __restrict__ ew,
               int* __restrict__ csr, int npairs)
{
  __shared__ float deg[ROWS];
  __shared__ int cnt[ROWS], cnt2[ROWS], rs[ROWS + 1];
  const int p = blockIdx.x, tid = threadIdx.x;
  const int Etot = npairs * EDG;
  int es = 0, ed = 0; float eww = 0.f;
  if (tid < ROWS){ deg[tid] = 1.0f; cnt[tid] = 0; cnt2[tid] = 0; }
  __syncthreads();
  if (tid < EDG){
    es  = ei[p * EDG + tid]        - p * ROWS;
    ed  = ei[Etot + p * EDG + tid] - p * ROWS;
    eww = ew[(tid >= EPG) ? (tid - EPG) : tid];
    atomicAdd(&deg[ed], eww);
    atomicAdd(&cnt[ed], 1);
  }
  __syncthreads();
  if (tid < ROWS) deg[tid] = rsqrtf(deg[tid]);
  if (tid < 64){                               // wave-0 inclusive scan
    int v = (tid < ROWS) ? cnt[tid] : 0;
#pragma unroll
    for (int off = 1; off < 64; off <<= 1){
      int n = __shfl_up(v, off, 64);
      if (tid >= off) v += n;
    }
    if (tid < ROWS) rs[tid + 1] = v;
    if (tid == 0)   rs[0] = 0;
  }
  __syncthreads();
  int* base = csr + (size_t)p * CSR_WORDS;
  if (tid < EDG){
    float nrm = deg[es] * eww * deg[ed];
    int slot = rs[ed] + atomicAdd(&cnt2[ed], 1);
    base[128 + slot] = es;
    ((float*)base)[240 + slot] = nrm;
  }
  if (tid < ROWS)  ((float*)base)[tid] = deg[tid];
  if (tid <= ROWS) base[64 + tid] = rs[tid];
}

// Main kernel: round-2 codegen shape (512 thr, 2 pairs, reg-prefetch
// pipeline, __launch_bounds__(512,4) -- the ONLY combo that held pf[8]
// across barriers without scratch spill), upgraded with global-wpack
// B-frags (no LDS W-tile) and pre-built CSR. LDS ~35 KB -> 4 blocks/CU.
__global__ __launch_bounds__(512, 4)
void gcn_main(const float* __restrict__ x, const float* __restrict__ bias,
              const float* __restrict__ gamma, const float* __restrict__ beta,
              float* __restrict__ out, const u16* __restrict__ wpack,
              const int* __restrict__ csr, int npairs)
{
  __shared__ alignas(16) u16 Hs[2][ROWS][LDW];  // 30.5 KB
  __shared__ float gbb[3][CH];                  // gamma, beta, bias
  __shared__ int cls[2][CSR_WORDS];             // staged CSR blobs (3 KB)

  const int tid  = threadIdx.x;
  const int s    = tid >> 8;          // which pair of the block (0/1)
  const int t256 = tid & 255;
  const int lane = tid & 63;
  const int wv4  = (tid >> 6) & 3;    // wave within pair
  const int hi   = lane >> 4;
  const int ngroups = npairs >> 1;

  float* dinv = (float*)&cls[s][0];
  int*   rsL  = &cls[s][64];
  int*   srcL = &cls[s][128];
  float* nrmL = (float*)&cls[s][240];

  if (tid < CH){
    gbb[0][tid] = gamma[tid]; gbb[1][tid] = beta[tid]; gbb[2][tid] = bias[tid];
  }

  const int arow = 16 * wv4 + (lane & 15);
  const int rowc = arow < ROWS ? arow : ROWS - 1;       // clamp pad rows
  const int xoff = hi * 8;

  // ---- prologue: prefetch first group's x rows + CSR blob ----
  f32x4 pf[8];
  {
    const int p0 = 2 * blockIdx.x + s;
    const float* xp = x + ((size_t)p0 * ROWS + rowc) * CH + xoff;
#pragma unroll
    for (int ks = 0; ks < 4; ks++){
      pf[2 * ks]     = *(const f32x4*)(xp + ks * 32);
      pf[2 * ks + 1] = *(const f32x4*)(xp + ks * 32 + 4);
    }
  }
  int cw0, cw1 = 0;
  {
    const int* cp = csr + (size_t)(2 * blockIdx.x + s) * CSR_WORDS;
    cw0 = cp[t256];
    if (t256 < CSR_WORDS - 256) cw1 = cp[256 + t256];
  }

  for (int q = blockIdx.x; q < ngroups; q += gridDim.x){
    const int p  = 2 * q + s;
    const int qn = q + gridDim.x;

    // ---- convert prefetched x -> A-frags (frees pf for next prefetch) ----
    bf16x8 afr[4];
#pragma unroll
    for (int ks = 0; ks < 4; ks++){
      f32x4 lo = pf[2 * ks], h4 = pf[2 * ks + 1];
      u16x8 t;
      t[0] = f2bf(lo[0]); t[1] = f2bf(lo[1]); t[2] = f2bf(lo[2]); t[3] = f2bf(lo[3]);
      t[4] = f2bf(h4[0]); t[5] = f2bf(h4[1]); t[6] = f2bf(h4[2]); t[7] = f2bf(h4[3]);
      afr[ks] = __builtin_bit_cast(bf16x8, t);
    }
    // ---- issue next group's x loads (overlap MFMA + epilogue) ----
    if (qn < ngroups){
      const float* xp = x + ((size_t)(2 * qn + s) * ROWS + rowc) * CH + xoff;
#pragma unroll
      for (int ks = 0; ks < 4; ks++){
        pf[2 * ks]     = *(const f32x4*)(xp + ks * 32);
        pf[2 * ks + 1] = *(const f32x4*)(xp + ks * 32 + 4);
      }
    }

    // ---- GEMM: B-frags from global wpack (L1-hot across blocks) ----
    f32x4 acc[8];
#pragma unroll
    for (int ct = 0; ct < 8; ct++){
      acc[ct] = (f32x4){0.f, 0.f, 0.f, 0.f};
#pragma unroll
      for (int ks = 0; ks < 4; ks++){
        u16x8 b = ((const u16x8*)wpack)[((ct << 2) + ks) * 64 + lane];
        acc[ct] = __builtin_amdgcn_mfma_f32_16x16x32_bf16(
                    afr[ks], __builtin_bit_cast(bf16x8, b), acc[ct], 0, 0, 0);
      }
    }

    __syncthreads();   // barrier 1: previous iteration's epilogue reads done

    // ---- write h to LDS ----
    {
      int r0 = 16 * wv4 + (hi << 2);
      int cc = lane & 15;
#pragma unroll
      for (int ct = 0; ct < 8; ct++){
#pragma unroll
        for (int r = 0; r < 4; r++){
          int rr = r0 + r;
          if (rr < ROWS) Hs[s][rr][16 * ct + cc] = f2bf(acc[ct][r]);
        }
      }
    }
    // ---- stage CSR blob, then issue next group's CSR loads ----
    cls[s][t256] = cw0;
    if (t256 < CSR_WORDS - 256) cls[s][256 + t256] = cw1;
    if (qn < ngroups){
      const int* cp = csr + (size_t)(2 * qn + s) * CSR_WORDS;
      cw0 = cp[t256];
      if (t256 < CSR_WORDS - 256) cw1 = cp[256 + t256];
    }
    __syncthreads();   // barrier 2: Hs + cls visible

    // ---- epilogue (scalar y0..y3, residual re-read from L2) ----
    const int half = lane >> 5;
    const int l32  = lane & 31;
    const int c0   = l32 * 4;
    for (int rp = wv4; rp < ROWS / 2; rp += 4){
      int row = 2 * rp + half;
      float dv = dinv[row];
      float d2 = dv * dv;                         // self-loop norm
      size_t gbase = ((size_t)p * ROWS + row) * CH + c0;
      u16x4 hs = *(const u16x4*)&Hs[s][row][c0];
      f32x4 xr = *(const f32x4*)(x + gbase);      // residual (L2-hot)
      f32x4 bb = *(const f32x4*)&gbb[2][c0];
      float y0 = bf2f(hs[0]) * d2 + bb[0] + xr[0];
      float y1 = bf2f(hs[1]) * d2 + bb[1] + xr[1];
      float y2 = bf2f(hs[2]) * d2 + bb[2] + xr[2];
      float y3 = bf2f(hs[3]) * d2 + bb[3] + xr[3];
      int e0 = rsL[row], e1 = rsL[row + 1];
      for (int i = e0; i < e1; i++){
        int sc = srcL[i]; float nm = nrmL[i];
        u16x4 hv = *(const u16x4*)&Hs[s][sc][c0];
        y0 += nm * bf2f(hv[0]);
        y1 += nm * bf2f(hv[1]);
        y2 += nm * bf2f(hv[2]);
        y3 += nm * bf2f(hv[3]);
      }
      float sm = y0 + y1 + y2 + y3;
      float sq = y0*y0 + y1*y1 + y2*y2 + y3*y3;
#pragma unroll
      for (int m = 1; m < 32; m <<= 1){
        sm += __shfl_xor(sm, m, 32);
        sq += __shfl_xor(sq, m, 32);
      }
      float mu   = sm * (1.0f / 128.0f);
      float var  = sq * (1.0f / 128.0f) - mu * mu;
      float rstd = rsqrtf(var + 1e-5f);
      f32x4 g4 = *(const f32x4*)&gbb[0][c0];
      f32x4 b4 = *(const f32x4*)&gbb[1][c0];
      f32x4 o;
      o[0] = fmaxf(0.f, (y0 - mu) * rstd * g4[0] + b4[0]);
      o[1] = fmaxf(0.f, (y1 - mu) * rstd * g4[1] + b4[1]);
      o[2] = fmaxf(0.f, (y2 - mu) * rstd * g4[2] + b4[2]);
      o[3] = fmaxf(0.f, (y3 - mu) * rstd * g4[3] + b4[3]);
      *(f32x4*)(out + gbase) = o;
    }
  }
}

// ---------------- fallback (round-5 kernel, proven) ----------------
__global__ __launch_bounds__(256, 4)
void gcn_fused(const float* __restrict__ x, const int* __restrict__ ei,
               const float* __restrict__ W, const float* __restrict__ bias,
               const float* __restrict__ ew, const float* __restrict__ gamma,
               const float* __restrict__ beta, float* __restrict__ out,
               const u16* __restrict__ wpack, int npairs)
{
  __shared__ alignas(16) u16 Hs[ROWS][LDW];
  __shared__ float gbb[3][CH];
  __shared__ float deg[ROWS];
  __shared__ int   cnt[ROWS], cnt2[ROWS], rs[ROWS + 1];
  __shared__ int   c_src[EDG];
  __shared__ float c_nrm[EDG];

  const int tid  = threadIdx.x;
  const int lane = tid & 63;
  const int wv   = tid >> 6;
  const int hi   = lane >> 4;
  const int p    = blockIdx.x;
  const int Etot = npairs * EDG;

  int es = 0, ed = 0; float eww = 0.f;
  if (tid < EDG){
    es  = ei[p * EDG + tid]        - p * ROWS;
    ed  = ei[Etot + p * EDG + tid] - p * ROWS;
    eww = ew[(tid >= EPG) ? (tid - EPG) : tid];
  }
  if (tid < ROWS){ deg[tid] = 1.0f; cnt[tid] = 0; cnt2[tid] = 0; }
  if (tid < CH){
    gbb[0][tid] = gamma[tid]; gbb[1][tid] = beta[tid]; gbb[2][tid] = bias[tid];
  }

  const int arow = 16 * wv + (lane & 15);
  const int rowc = arow < ROWS ? arow : ROWS - 1;
  const float* xp = x + ((size_t)p * ROWS + rowc) * CH + hi * 8;

  f32x4 acc[8];
  {
    bf16x8 afr[4];
#pragma unroll
    for (int ks = 0; ks < 4; ks++){
      f32x4 lo = *(const f32x4*)(xp + ks * 32);
      f32x4 h4 = *(const f32x4*)(xp + ks * 32 + 4);
      u16x8 t;
      t[0] = f2bf(lo[0]); t[1] = f2bf(lo[1]); t[2] = f2bf(lo[2]); t[3] = f2bf(lo[3]);
      t[4] = f2bf(h4[0]); t[5] = f2bf(h4[1]); t[6] = f2bf(h4[2]); t[7] = f2bf(h4[3]);
      afr[ks] = __builtin_bit_cast(bf16x8, t);
    }
#pragma unroll
    for (int ct = 0; ct < 8; ct++){
      acc[ct] = (f32x4){0.f, 0.f, 0.f, 0.f};
#pragma unroll
      for (int ks = 0; ks < 4; ks++){
        u16x8 b;
        if (wpack){
          b = ((const u16x8*)wpack)[((ct << 2) + ks) * 64 + lane];
        } else {
#pragma unroll
          for (int j = 0; j < 8; j++){
            int k = hi * 8 + ks * 32 + j;
            int c = ct * 16 + (lane & 15);
            b[j] = f2bf(W[k * CH + c]);
          }
        }
        acc[ct] = __builtin_amdgcn_mfma_f32_16x16x32_bf16(
                    afr[ks], __builtin_bit_cast(bf16x8, b), acc[ct], 0, 0, 0);
      }
    }
  }

  {
    int r0 = 16 * wv + (hi << 2);
    int cc = lane & 15;
#pragma unroll
    for (int ct = 0; ct < 8; ct++){
#pragma unroll
      for (int r = 0; r < 4; r++){
        int rr = r0 + r;
        if (rr < ROWS) Hs[rr][16 * ct + cc] = f2bf(acc[ct][r]);
      }
    }
  }
  __syncthreads();

  if (tid < EDG){
    atomicAdd(&deg[ed], eww);
    atomicAdd(&cnt[ed], 1);
  }
  __syncthreads();

  if (tid < ROWS) deg[tid] = rsqrtf(deg[tid]);
  if (wv == 0){
    int v = (lane < ROWS) ? cnt[lane] : 0;
#pragma unroll
    for (int off = 1; off < 64; off <<= 1){
      int n = __shfl_up(v, off, 64);
      if (lane >= off) v += n;
    }
    if (lane < ROWS) rs[lane + 1] = v;
    if (lane == 0)   rs[0] = 0;
  }
  __syncthreads();

  if (tid < EDG){
    float nrm = deg[es] * eww * deg[ed];
    int slot = rs[ed] + atomicAdd(&cnt2[ed], 1);
    c_src[slot] = es;
    c_nrm[slot] = nrm;
  }
  __syncthreads();

  const int half = lane >> 5;
  const int l32  = lane & 31;
  const int c0   = l32 * 4;
  for (int rp = wv; rp < ROWS / 2; rp += 4){
    int row = 2 * rp + half;
    float dv = deg[row];
    float d2 = dv * dv;
    size_t gbase = ((size_t)p * ROWS + row) * CH + c0;
    u16x4 hs = *(const u16x4*)&Hs[row][c0];
    f32x4 xr = *(const f32x4*)(x + gbase);
    f32x4 bb = *(const f32x4*)&gbb[2][c0];
    float y0 = bf2f(hs[0]) * d2 + bb[0] + xr[0];
    float y1 = bf2f(hs[1]) * d2 + bb[1] + xr[1];
    float y2 = bf2f(hs[2]) * d2 + bb[2] + xr[2];
    float y3 = bf2f(hs[3]) * d2 + bb[3] + xr[3];
    int s0 = rs[row], s1 = rs[row + 1];
    for (int i = s0; i < s1; i++){
      int sc = c_src[i]; float nm = c_nrm[i];
      u16x4 hv = *(const u16x4*)&Hs[sc][c0];
      y0 += nm * bf2f(hv[0]);
      y1 += nm * bf2f(hv[1]);
      y2 += nm * bf2f(hv[2]);
      y3 += nm * bf2f(hv[3]);
    }
    float sm = y0 + y1 + y2 + y3;
    float sq = y0*y0 + y1*y1 + y2*y2 + y3*y3;
#pragma unroll
    for (int m = 1; m < 32; m <<= 1){
      sm += __shfl_xor(sm, m, 32);
      sq += __shfl_xor(sq, m, 32);
    }
    float mu   = sm * (1.0f / 128.0f);
    float var  = sq * (1.0f / 128.0f) - mu * mu;
    float rstd = rsqrtf(var + 1e-5f);
    f32x4 g4 = *(const f32x4*)&gbb[0][c0];
    f32x4 b4 = *(const f32x4*)&gbb[1][c0];
    f32x4 o;
    o[0] = fmaxf(0.f, (y0 - mu) * rstd * g4[0] + b4[0]);
    o[1] = fmaxf(0.f, (y1 - mu) * rstd * g4[1] + b4[1]);
    o[2] = fmaxf(0.f, (y2 - mu) * rstd * g4[2] + b4[2]);
    o[3] = fmaxf(0.f, (y3 - mu) * rstd * g4[3] + b4[3]);
    *(f32x4*)(out + gbase) = o;
  }
}

extern "C" void kernel_launch(void* const* d_in, const int* in_sizes, int n_in,
                              void* d_out, int out_size, void* d_ws, size_t ws_size,
                              hipStream_t stream)
{
  const float* x     = (const float*)d_in[0];
  const int*   ei    = (const int*)d_in[1];
  const float* W     = (const float*)d_in[2];
  const float* bias  = (const float*)d_in[3];
  const float* ew    = (const float*)d_in[4];
  const float* gamma = (const float*)d_in[5];
  const float* beta  = (const float*)d_in[6];
  float* out = (float*)d_out;

  int N = in_sizes[0] / CH;          // 458752
  int npairs = N / ROWS;             // 8192
  int ngroups = npairs / 2;          // 4096

  const size_t wpack_bytes = (size_t)CH * CH * sizeof(u16);       // 32 KB
  const size_t csr_bytes   = (size_t)npairs * CSR_WORDS * 4;      // 12.6 MB

  if (ws_size >= wpack_bytes + csr_bytes){
    u16* wpack = (u16*)d_ws;
    int* csr   = (int*)((char*)d_ws + wpack_bytes);
    hipLaunchKernelGGL(pack_w, dim3(CH * CH / 256), dim3(256), 0, stream, W, wpack);
    hipLaunchKernelGGL(build_csr, dim3(npairs), dim3(128), 0, stream, ei, ew, csr, npairs);
    int grid = ngroups < 1024 ? ngroups : 1024;
    hipLaunchKernelGGL(gcn_main, dim3(grid), dim3(512), 0, stream,
                       x, bias, gamma, beta, out, wpack, csr, npairs);
  } else {
    u16* wpack = nullptr;
    if (ws_size >= wpack_bytes){
      wpack = (u16*)d_ws;
      hipLaunchKernelGGL(pack_w, dim3(CH * CH / 256), dim3(256), 0, stream, W, wpack);
    }
    hipLaunchKernelGGL(gcn_fused, dim3(npairs), dim3(256), 0, stream,
                       x, ei, W, bias, ew, gamma, beta, out, wpack, npairs);
  }
}

// Round 9
// 287.335 us; speedup vs baseline: 1.0666x; 1.0666x over previous
//
#include <hip/hip_runtime.h>

#define EPG 56
#define ROWS 56      // rows per pair (2 graphs)
#define EDG 112      // edges per pair
#define CH 128
#define LDW 136      // Hs leading dim (bf16 elems), +8 pad

// CSR blob layout per pair (int32 words): dinv f32 @0(56), rs @64(57),
// src @128(112), nrm f32 @240(112). Stride 384 words = 1536 B.
#define CSR_WORDS 384

typedef float f32x4 __attribute__((ext_vector_type(4)));
typedef __bf16 bf16x8 __attribute__((ext_vector_type(8)));
typedef unsigned short u16;
typedef u16 u16x8 __attribute__((ext_vector_type(8)));
typedef u16 u16x4 __attribute__((ext_vector_type(4)));

__device__ __forceinline__ u16 f2bf(float f){
  union { float f; unsigned u; } v; v.f = f;
  unsigned r = (v.u + 0x7fffu + ((v.u >> 16) & 1u)) >> 16;  // RNE
  return (u16)r;
}
__device__ __forceinline__ float bf2f(u16 h){
  union { unsigned u; float f; } v; v.u = ((unsigned)h) << 16;
  return v.f;
}

// Pack W (f32 [128][128], row k, col c) into MFMA B-fragment order, bf16:
// wp[((ct*4+ks)*64 + l)*8 + j] = bf16( W[(l>>4)*8 + ks*32 + j][ct*16 + (l&15)] )
__global__ void pack_w(const float* __restrict__ W, u16* __restrict__ wp){
  int d = blockIdx.x * 256 + threadIdx.x;           // 0..16383
  int j  = d & 7;
  int l  = (d >> 3) & 63;
  int ks = (d >> 9) & 3;
  int ct = d >> 11;
  int k = ((l >> 4) << 3) + (ks << 5) + j;
  int c = (ct << 4) + (l & 15);
  wp[d] = f2bf(W[k * CH + c]);
}

// Pre-pass: per-pair degree/norm/CSR into d_ws.
__global__ __launch_bounds__(128)
void build_csr(const int* __restrict__ ei, const float* __restrict__ ew,
               int* __restrict__ csr, int npairs)
{
  __shared__ float deg[ROWS];
  __shared__ int cnt[ROWS], cnt2[ROWS], rs[ROWS + 1];
  const int p = blockIdx.x, tid = threadIdx.x;
  const int Etot = npairs * EDG;
  int es = 0, ed = 0; float eww = 0.f;
  if (tid < ROWS){ deg[tid] = 1.0f; cnt[tid] = 0; cnt2[tid] = 0; }
  __syncthreads();
  if (tid < EDG){
    es  = ei[p * EDG + tid]        - p * ROWS;
    ed  = ei[Etot + p * EDG + tid] - p * ROWS;
    eww = ew[(tid >= EPG) ? (tid - EPG) : tid];
    atomicAdd(&deg[ed], eww);
    atomicAdd(&cnt[ed], 1);
  }
  __syncthreads();
  if (tid < ROWS) deg[tid] = rsqrtf(deg[tid]);
  if (tid < 64){                               // wave-0 inclusive scan
    int v = (tid < ROWS) ? cnt[tid] : 0;
#pragma unroll
    for (int off = 1; off < 64; off <<= 1){
      int n = __shfl_up(v, off, 64);
      if (tid >= off) v += n;
    }
    if (tid < ROWS) rs[tid + 1] = v;
    if (tid == 0)   rs[0] = 0;
  }
  __syncthreads();
  int* base = csr + (size_t)p * CSR_WORDS;
  if (tid < EDG){
    float nrm = deg[es] * eww * deg[ed];
    int slot = rs[ed] + atomicAdd(&cnt2[ed], 1);
    base[128 + slot] = es;
    ((float*)base)[240 + slot] = nrm;
  }
  if (tid < ROWS)  ((float*)base)[tid] = deg[tid];
  if (tid <= ROWS) base[64 + tid] = rs[tid];
}

// Main kernel. Register-pressure-phased pipeline:
//   convert pf->afr ; barrier1 ; GEMM with per-ct fused Hs write (one acc
//   live at a time, round-5 lean codegen) ; prefetch next pf/cw (round-2
//   position: overlaps CSR stage + epilogue, NOT the GEMM) ; barrier2 ;
//   epilogue. Peak live ~55-60 regs -> fits 64-VGPR / 8-waves-per-EU.
__global__ __launch_bounds__(512, 4)
void gcn_main(const float* __restrict__ x, const float* __restrict__ bias,
              const float* __restrict__ gamma, const float* __restrict__ beta,
              float* __restrict__ out, const u16* __restrict__ wpack,
              const int* __restrict__ csr, int npairs)
{
  __shared__ alignas(16) u16 Hs[2][ROWS][LDW];  // 30.5 KB
  __shared__ float gbb[3][CH];                  // gamma, beta, bias
  __shared__ int cls[2][CSR_WORDS];             // staged CSR blobs (3 KB)

  const int tid  = threadIdx.x;
  const int s    = tid >> 8;          // which pair of the block (0/1)
  const int t256 = tid & 255;
  const int lane = tid & 63;
  const int wv4  = (tid >> 6) & 3;    // wave within pair
  const int hi   = lane >> 4;
  const int ngroups = npairs >> 1;

  float* dinv = (float*)&cls[s][0];
  int*   rsL  = &cls[s][64];
  int*   srcL = &cls[s][128];
  float* nrmL = (float*)&cls[s][240];

  if (tid < CH){
    gbb[0][tid] = gamma[tid]; gbb[1][tid] = beta[tid]; gbb[2][tid] = bias[tid];
  }

  const int arow = 16 * wv4 + (lane & 15);
  const int rowc = arow < ROWS ? arow : ROWS - 1;       // clamp pad rows
  const int xoff = hi * 8;

  // ---- prologue: prefetch first group's x rows + CSR blob ----
  f32x4 pf[8];
  {
    const int p0 = 2 * blockIdx.x + s;
    const float* xp = x + ((size_t)p0 * ROWS + rowc) * CH + xoff;
#pragma unroll
    for (int ks = 0; ks < 4; ks++){
      pf[2 * ks]     = *(const f32x4*)(xp + ks * 32);
      pf[2 * ks + 1] = *(const f32x4*)(xp + ks * 32 + 4);
    }
  }
  int cw0, cw1 = 0;
  {
    const int* cp = csr + (size_t)(2 * blockIdx.x + s) * CSR_WORDS;
    cw0 = cp[t256];
    if (t256 < CSR_WORDS - 256) cw1 = cp[256 + t256];
  }

  for (int q = blockIdx.x; q < ngroups; q += gridDim.x){
    const int p  = 2 * q + s;
    const int qn = q + gridDim.x;

    // ---- convert prefetched x -> A-frags (pf dies; overlaps barrier) ----
    bf16x8 afr[4];
#pragma unroll
    for (int ks = 0; ks < 4; ks++){
      f32x4 lo = pf[2 * ks], h4 = pf[2 * ks + 1];
      u16x8 t;
      t[0] = f2bf(lo[0]); t[1] = f2bf(lo[1]); t[2] = f2bf(lo[2]); t[3] = f2bf(lo[3]);
      t[4] = f2bf(h4[0]); t[5] = f2bf(h4[1]); t[6] = f2bf(h4[2]); t[7] = f2bf(h4[3]);
      afr[ks] = __builtin_bit_cast(bf16x8, t);
    }

    __syncthreads();   // barrier 1: prev iteration's epilogue reads done

    // ---- GEMM fused with Hs write: one acc[ct] live at a time ----
    {
      const int r0 = 16 * wv4 + (hi << 2);
      const int cc = lane & 15;
#pragma unroll
      for (int ct = 0; ct < 8; ct++){
        f32x4 a = (f32x4){0.f, 0.f, 0.f, 0.f};
#pragma unroll
        for (int ks = 0; ks < 4; ks++){
          u16x8 b = ((const u16x8*)wpack)[((ct << 2) + ks) * 64 + lane];
          a = __builtin_amdgcn_mfma_f32_16x16x32_bf16(
                afr[ks], __builtin_bit_cast(bf16x8, b), a, 0, 0, 0);
        }
#pragma unroll
        for (int r = 0; r < 4; r++){
          int rr = r0 + r;
          if (rr < ROWS) Hs[s][rr][16 * ct + cc] = f2bf(a[r]);
        }
      }
    }

    // ---- prefetch next group's x (overlaps CSR stage + epilogue) ----
    if (qn < ngroups){
      const float* xp = x + ((size_t)(2 * qn + s) * ROWS + rowc) * CH + xoff;
#pragma unroll
      for (int ks = 0; ks < 4; ks++){
        pf[2 * ks]     = *(const f32x4*)(xp + ks * 32);
        pf[2 * ks + 1] = *(const f32x4*)(xp + ks * 32 + 4);
      }
    }
    // ---- stage CSR blob, then issue next group's CSR loads ----
    cls[s][t256] = cw0;
    if (t256 < CSR_WORDS - 256) cls[s][256 + t256] = cw1;
    if (qn < ngroups){
      const int* cp = csr + (size_t)(2 * qn + s) * CSR_WORDS;
      cw0 = cp[t256];
      if (t256 < CSR_WORDS - 256) cw1 = cp[256 + t256];
    }
    __syncthreads();   // barrier 2: Hs + cls visible

    // ---- epilogue (scalar y0..y3, residual re-read from L2) ----
    const int half = lane >> 5;
    const int l32  = lane & 31;
    const int c0   = l32 * 4;
    for (int rp = wv4; rp < ROWS / 2; rp += 4){
      int row = 2 * rp + half;
      float dv = dinv[row];
      float d2 = dv * dv;                         // self-loop norm
      size_t gbase = ((size_t)p * ROWS + row) * CH + c0;
      u16x4 hs = *(const u16x4*)&Hs[s][row][c0];
      f32x4 xr = *(const f32x4*)(x + gbase);      // residual (L2-hot)
      f32x4 bb = *(const f32x4*)&gbb[2][c0];
      float y0 = bf2f(hs[0]) * d2 + bb[0] + xr[0];
      float y1 = bf2f(hs[1]) * d2 + bb[1] + xr[1];
      float y2 = bf2f(hs[2]) * d2 + bb[2] + xr[2];
      float y3 = bf2f(hs[3]) * d2 + bb[3] + xr[3];
      int e0 = rsL[row], e1 = rsL[row + 1];
      for (int i = e0; i < e1; i++){
        int sc = srcL[i]; float nm = nrmL[i];
        u16x4 hv = *(const u16x4*)&Hs[s][sc][c0];
        y0 += nm * bf2f(hv[0]);
        y1 += nm * bf2f(hv[1]);
        y2 += nm * bf2f(hv[2]);
        y3 += nm * bf2f(hv[3]);
      }
      float sm = y0 + y1 + y2 + y3;
      float sq = y0*y0 + y1*y1 + y2*y2 + y3*y3;
#pragma unroll
      for (int m = 1; m < 32; m <<= 1){
        sm += __shfl_xor(sm, m, 32);
        sq += __shfl_xor(sq, m, 32);
      }
      float mu   = sm * (1.0f / 128.0f);
      float var  = sq * (1.0f / 128.0f) - mu * mu;
      float rstd = rsqrtf(var + 1e-5f);
      f32x4 g4 = *(const f32x4*)&gbb[0][c0];
      f32x4 b4 = *(const f32x4*)&gbb[1][c0];
      f32x4 o;
      o[0] = fmaxf(0.f, (y0 - mu) * rstd * g4[0] + b4[0]);
      o[1] = fmaxf(0.f, (y1 - mu) * rstd * g4[1] + b4[1]);
      o[2] = fmaxf(0.f, (y2 - mu) * rstd * g4[2] + b4[2]);
      o[3] = fmaxf(0.f, (y3 - mu) * rstd * g4[3] + b4[3]);
      *(f32x4*)(out + gbase) = o;
    }
  }
}

// ---------------- fallback (round-5 kernel, proven) ----------------
__global__ __launch_bounds__(256, 4)
void gcn_fused(const float* __restrict__ x, const int* __restrict__ ei,
               const float* __restrict__ W, const float* __restrict__ bias,
               const float* __restrict__ ew, const float* __restrict__ gamma,
               const float* __restrict__ beta, float* __restrict__ out,
               const u16* __restrict__ wpack, int npairs)
{
  __shared__ alignas(16) u16 Hs[ROWS][LDW];
  __shared__ float gbb[3][CH];
  __shared__ float deg[ROWS];
  __shared__ int   cnt[ROWS], cnt2[ROWS], rs[ROWS + 1];
  __shared__ int   c_src[EDG];
  __shared__ float c_nrm[EDG];

  const int tid  = threadIdx.x;
  const int lane = tid & 63;
  const int wv   = tid >> 6;
  const int hi   = lane >> 4;
  const int p    = blockIdx.x;
  const int Etot = npairs * EDG;

  int es = 0, ed = 0; float eww = 0.f;
  if (tid < EDG){
    es  = ei[p * EDG + tid]        - p * ROWS;
    ed  = ei[Etot + p * EDG + tid] - p * ROWS;
    eww = ew[(tid >= EPG) ? (tid - EPG) : tid];
  }
  if (tid < ROWS){ deg[tid] = 1.0f; cnt[tid] = 0; cnt2[tid] = 0; }
  if (tid < CH){
    gbb[0][tid] = gamma[tid]; gbb[1][tid] = beta[tid]; gbb[2][tid] = bias[tid];
  }

  const int arow = 16 * wv + (lane & 15);
  const int rowc = arow < ROWS ? arow : ROWS - 1;
  const float* xp = x + ((size_t)p * ROWS + rowc) * CH + hi * 8;

  f32x4 acc[8];
  {
    bf16x8 afr[4];
#pragma unroll
    for (int ks = 0; ks < 4; ks++){
      f32x4 lo = *(const f32x4*)(xp + ks * 32);
      f32x4 h4 = *(const f32x4*)(xp + ks * 32 + 4);
      u16x8 t;
      t[0] = f2bf(lo[0]); t[1] = f2bf(lo[1]); t[2] = f2bf(lo[2]); t[3] = f2bf(lo[3]);
      t[4] = f2bf(h4[0]); t[5] = f2bf(h4[1]); t[6] = f2bf(h4[2]); t[7] = f2bf(h4[3]);
      afr[ks] = __builtin_bit_cast(bf16x8, t);
    }
#pragma unroll
    for (int ct = 0; ct < 8; ct++){
      acc[ct] = (f32x4){0.f, 0.f, 0.f, 0.f};
#pragma unroll
      for (int ks = 0; ks < 4; ks++){
        u16x8 b;
        if (wpack){
          b = ((const u16x8*)wpack)[((ct << 2) + ks) * 64 + lane];
        } else {
#pragma unroll
          for (int j = 0; j < 8; j++){
            int k = hi * 8 + ks * 32 + j;
            int c = ct * 16 + (lane & 15);
            b[j] = f2bf(W[k * CH + c]);
          }
        }
        acc[ct] = __builtin_amdgcn_mfma_f32_16x16x32_bf16(
                    afr[ks], __builtin_bit_cast(bf16x8, b), acc[ct], 0, 0, 0);
      }
    }
  }

  {
    int r0 = 16 * wv + (hi << 2);
    int cc = lane & 15;
#pragma unroll
    for (int ct = 0; ct < 8; ct++){
#pragma unroll
      for (int r = 0; r < 4; r++){
        int rr = r0 + r;
        if (rr < ROWS) Hs[rr][16 * ct + cc] = f2bf(acc[ct][r]);
      }
    }
  }
  __syncthreads();

  if (tid < EDG){
    atomicAdd(&deg[ed], eww);
    atomicAdd(&cnt[ed], 1);
  }
  __syncthreads();

  if (tid < ROWS) deg[tid] = rsqrtf(deg[tid]);
  if (wv == 0){
    int v = (lane < ROWS) ? cnt[lane] : 0;
#pragma unroll
    for (int off = 1; off < 64; off <<= 1){
      int n = __shfl_up(v, off, 64);
      if (lane >= off) v += n;
    }
    if (lane < ROWS) rs[lane + 1] = v;
    if (lane == 0)   rs[0] = 0;
  }
  __syncthreads();

  if (tid < EDG){
    float nrm = deg[es] * eww * deg[ed];
    int slot = rs[ed] + atomicAdd(&cnt2[ed], 1);
    c_src[slot] = es;
    c_nrm[slot] = nrm;
  }
  __syncthreads();

  const int half = lane >> 5;
  const int l32  = lane & 31;
  const int c0   = l32 * 4;
  for (int rp = wv; rp < ROWS / 2; rp += 4){
    int row = 2 * rp + half;
    float dv = deg[row];
    float d2 = dv * dv;
    size_t gbase = ((size_t)p * ROWS + row) * CH + c0;
    u16x4 hs = *(const u16x4*)&Hs[row][c0];
    f32x4 xr = *(const f32x4*)(x + gbase);
    f32x4 bb = *(const f32x4*)&gbb[2][c0];
    float y0 = bf2f(hs[0]) * d2 + bb[0] + xr[0];
    float y1 = bf2f(hs[1]) * d2 + bb[1] + xr[1];
    float y2 = bf2f(hs[2]) * d2 + bb[2] + xr[2];
    float y3 = bf2f(hs[3]) * d2 + bb[3] + xr[3];
    int s0 = rs[row], s1 = rs[row + 1];
    for (int i = s0; i < s1; i++){
      int sc = c_src[i]; float nm = c_nrm[i];
      u16x4 hv = *(const u16x4*)&Hs[sc][c0];
      y0 += nm * bf2f(hv[0]);
      y1 += nm * bf2f(hv[1]);
      y2 += nm * bf2f(hv[2]);
      y3 += nm * bf2f(hv[3]);
    }
    float sm = y0 + y1 + y2 + y3;
    float sq = y0*y0 + y1*y1 + y2*y2 + y3*y3;
#pragma unroll
    for (int m = 1; m < 32; m <<= 1){
      sm += __shfl_xor(sm, m, 32);
      sq += __shfl_xor(sq, m, 32);
    }
    float mu   = sm * (1.0f / 128.0f);
    float var  = sq * (1.0f / 128.0f) - mu * mu;
    float rstd = rsqrtf(var + 1e-5f);
    f32x4 g4 = *(const f32x4*)&gbb[0][c0];
    f32x4 b4 = *(const f32x4*)&gbb[1][c0];
    f32x4 o;
    o[0] = fmaxf(0.f, (y0 - mu) * rstd * g4[0] + b4[0]);
    o[1] = fmaxf(0.f, (y1 - mu) * rstd * g4[1] + b4[1]);
    o[2] = fmaxf(0.f, (y2 - mu) * rstd * g4[2] + b4[2]);
    o[3] = fmaxf(0.f, (y3 - mu) * rstd * g4[3] + b4[3]);
    *(f32x4*)(out + gbase) = o;
  }
}

extern "C" void kernel_launch(void* const* d_in, const int* in_sizes, int n_in,
                              void* d_out, int out_size, void* d_ws, size_t ws_size,
                              hipStream_t stream)
{
  const float* x     = (const float*)d_in[0];
  const int*   ei    = (const int*)d_in[1];
  const float* W     = (const float*)d_in[2];
  const float* bias  = (const float*)d_in[3];
  const float* ew    = (const float*)d_in[4];
  const float* gamma = (const float*)d_in[5];
  const float* beta  = (const float*)d_in[6];
  float* out = (float*)d_out;

  int N = in_sizes[0] / CH;          // 458752
  int npairs = N / ROWS;             // 8192
  int ngroups = npairs / 2;          // 4096

  const size_t wpack_bytes = (size_t)CH * CH * sizeof(u16);       // 32 KB
  const size_t csr_bytes   = (size_t)npairs * CSR_WORDS * 4;      // 12.6 MB

  if (ws_size >= wpack_bytes + csr_bytes){
    u16* wpack = (u16*)d_ws;
    int* csr   = (int*)((char*)d_ws + wpack_bytes);
    hipLaunchKernelGGL(pack_w, dim3(CH * CH / 256), dim3(256), 0, stream, W, wpack);
    hipLaunchKernelGGL(build_csr, dim3(npairs), dim3(128), 0, stream, ei, ew, csr, npairs);
    int grid = ngroups < 1024 ? ngroups : 1024;
    hipLaunchKernelGGL(gcn_main, dim3(grid), dim3(512), 0, stream,
                       x, bias, gamma, beta, out, wpack, csr, npairs);
  } else {
    u16* wpack = nullptr;
    if (ws_size >= wpack_bytes){
      wpack = (u16*)d_ws;
      hipLaunchKernelGGL(pack_w, dim3(CH * CH / 256), dim3(256), 0, stream, W, wpack);
    }
    hipLaunchKernelGGL(gcn_fused, dim3(npairs), dim3(256), 0, stream,
                       x, ei, W, bias, ew, gamma, beta, out, wpack, npairs);
  }
}

// Round 10
// 157.939 us; speedup vs baseline: 1.9405x; 1.8193x over previous
//
#include <hip/hip_runtime.h>

#define EPG 56
#define ROWS 56      // rows per pair (2 graphs)
#define EDG 112      // edges per pair
#define CH 128
#define LDW 136      // Hs leading dim (bf16 elems), +8 pad

// CSR blob layout per pair (int32 words): d2 (=dinv^2) f32 @0(56), rs @64(57),
// src @128(112), nrm f32 @240(112). Stride 384 words = 1536 B.
#define CSR_WORDS 384

typedef float f32x4 __attribute__((ext_vector_type(4)));
typedef __bf16 bf16x8 __attribute__((ext_vector_type(8)));
typedef unsigned short u16;
typedef u16 u16x8 __attribute__((ext_vector_type(8)));
typedef u16 u16x4 __attribute__((ext_vector_type(4)));

__device__ __forceinline__ u16 f2bf(float f){
  union { float f; unsigned u; } v; v.f = f;
  unsigned r = (v.u + 0x7fffu + ((v.u >> 16) & 1u)) >> 16;  // RNE
  return (u16)r;
}
__device__ __forceinline__ float bf2f(u16 h){
  union { unsigned u; float f; } v; v.u = ((unsigned)h) << 16;
  return v.f;
}

// Pack W (f32 [128][128], row k, col c) into MFMA B-fragment order, bf16:
// wp[((ct*4+ks)*64 + l)*8 + j] = bf16( W[(l>>4)*8 + ks*32 + j][ct*16 + (l&15)] )
__global__ void pack_w(const float* __restrict__ W, u16* __restrict__ wp){
  int d = blockIdx.x * 256 + threadIdx.x;           // 0..16383
  int j  = d & 7;
  int l  = (d >> 3) & 63;
  int ks = (d >> 9) & 3;
  int ct = d >> 11;
  int k = ((l >> 4) << 3) + (ks << 5) + j;
  int c = (ct << 4) + (l & 15);
  wp[d] = f2bf(W[k * CH + c]);
}

// Pre-pass: per-pair degree/norm/CSR into d_ws. Slot 0..55 holds dinv^2
// (the self-loop norm the epilogue consumes directly).
__global__ __launch_bounds__(128)
void build_csr(const int* __restrict__ ei, const float* __restrict__ ew,
               int* __restrict__ csr, int npairs)
{
  __shared__ float deg[ROWS];
  __shared__ int cnt[ROWS], cnt2[ROWS], rs[ROWS + 1];
  const int p = blockIdx.x, tid = threadIdx.x;
  const int Etot = npairs * EDG;
  int es = 0, ed = 0; float eww = 0.f;
  if (tid < ROWS){ deg[tid] = 1.0f; cnt[tid] = 0; cnt2[tid] = 0; }
  __syncthreads();
  if (tid < EDG){
    es  = ei[p * EDG + tid]        - p * ROWS;
    ed  = ei[Etot + p * EDG + tid] - p * ROWS;
    eww = ew[(tid >= EPG) ? (tid - EPG) : tid];
    atomicAdd(&deg[ed], eww);
    atomicAdd(&cnt[ed], 1);
  }
  __syncthreads();
  if (tid < ROWS) deg[tid] = rsqrtf(deg[tid]);
  if (tid < 64){                               // wave-0 inclusive scan
    int v = (tid < ROWS) ? cnt[tid] : 0;
#pragma unroll
    for (int off = 1; off < 64; off <<= 1){
      int n = __shfl_up(v, off, 64);
      if (tid >= off) v += n;
    }
    if (tid < ROWS) rs[tid + 1] = v;
    if (tid == 0)   rs[0] = 0;
  }
  __syncthreads();
  int* base = csr + (size_t)p * CSR_WORDS;
  if (tid < EDG){
    float nrm = deg[es] * eww * deg[ed];
    int slot = rs[ed] + atomicAdd(&cnt2[ed], 1);
    base[128 + slot] = es;
    ((float*)base)[240 + slot] = nrm;
  }
  if (tid < ROWS)  ((float*)base)[tid] = deg[tid] * deg[tid];   // dinv^2
  if (tid <= ROWS) base[64 + tid] = rs[tid];
}

// Main kernel: one pair per 256-thread block, ONE barrier total.
//   {issue cls + gbb + A-frag loads} -> GEMM (per-ct fused Hs write, one
//   acc live at a time) -> stage cls -> barrier -> epilogue.
// No register state held across the barrier beyond loop scalars: the
// round-5 lean codegen (VGPR 36, zero spill) with 4 fewer barriers and
// no edge atomics/scan on the critical path. 18.2 KB LDS -> 8 blocks/CU.
__global__ __launch_bounds__(256, 4)
void gcn_main(const float* __restrict__ x, const float* __restrict__ bias,
              const float* __restrict__ gamma, const float* __restrict__ beta,
              float* __restrict__ out, const u16* __restrict__ wpack,
              const int* __restrict__ csr, int npairs)
{
  __shared__ alignas(16) u16 Hs[ROWS][LDW];   // 14.9 KB
  __shared__ float gbb[3][CH];                // gamma, beta, bias
  __shared__ int cls[CSR_WORDS];              // CSR blob (1.5 KB)

  float* d2L  = (float*)&cls[0];
  int*   rsL  = &cls[64];
  int*   srcL = &cls[128];
  float* nrmL = (float*)&cls[240];

  const int tid  = threadIdx.x;
  const int lane = tid & 63;
  const int wv   = tid >> 6;
  const int hi   = lane >> 4;
  const int p    = blockIdx.x;

  // ---- issue CSR-blob loads (latency hidden under A-load + GEMM) ----
  const int* cp = csr + (size_t)p * CSR_WORDS;
  int cw0 = cp[tid];
  int cw1 = (tid < CSR_WORDS - 256) ? cp[256 + tid] : 0;

  if (tid < CH){
    gbb[0][tid] = gamma[tid]; gbb[1][tid] = beta[tid]; gbb[2][tid] = bias[tid];
  }

  // ---- A-fragments straight from global x ----
  const int arow = 16 * wv + (lane & 15);
  const int rowc = arow < ROWS ? arow : ROWS - 1;       // clamp pad rows
  const float* xp = x + ((size_t)p * ROWS + rowc) * CH + hi * 8;

  bf16x8 afr[4];
#pragma unroll
  for (int ks = 0; ks < 4; ks++){
    f32x4 lo = *(const f32x4*)(xp + ks * 32);
    f32x4 h4 = *(const f32x4*)(xp + ks * 32 + 4);
    u16x8 t;
    t[0] = f2bf(lo[0]); t[1] = f2bf(lo[1]); t[2] = f2bf(lo[2]); t[3] = f2bf(lo[3]);
    t[4] = f2bf(h4[0]); t[5] = f2bf(h4[1]); t[6] = f2bf(h4[2]); t[7] = f2bf(h4[3]);
    afr[ks] = __builtin_bit_cast(bf16x8, t);
  }

  // ---- GEMM fused with Hs write: one acc[ct] live at a time ----
  {
    const int r0 = 16 * wv + (hi << 2);
    const int cc = lane & 15;
#pragma unroll
    for (int ct = 0; ct < 8; ct++){
      f32x4 a = (f32x4){0.f, 0.f, 0.f, 0.f};
#pragma unroll
      for (int ks = 0; ks < 4; ks++){
        u16x8 b = ((const u16x8*)wpack)[((ct << 2) + ks) * 64 + lane];
        a = __builtin_amdgcn_mfma_f32_16x16x32_bf16(
              afr[ks], __builtin_bit_cast(bf16x8, b), a, 0, 0, 0);
      }
#pragma unroll
      for (int r = 0; r < 4; r++){
        int rr = r0 + r;
        if (rr < ROWS) Hs[rr][16 * ct + cc] = f2bf(a[r]);
      }
    }
  }

  // ---- stage CSR blob ----
  cls[tid] = cw0;
  if (tid < CSR_WORDS - 256) cls[256 + tid] = cw1;

  __syncthreads();   // the ONLY barrier: Hs + cls + gbb visible

  // ---- epilogue (scalar y0..y3, residual re-read from L2/L3) ----
  const int half = lane >> 5;
  const int l32  = lane & 31;
  const int c0   = l32 * 4;
  for (int rp = wv; rp < ROWS / 2; rp += 4){
    int row = 2 * rp + half;
    float d2 = d2L[row];                        // dinv^2 (self-loop norm)
    size_t gbase = ((size_t)p * ROWS + row) * CH + c0;
    u16x4 hs = *(const u16x4*)&Hs[row][c0];
    f32x4 xr = *(const f32x4*)(x + gbase);      // residual (L2/L3-hot)
    f32x4 bb = *(const f32x4*)&gbb[2][c0];
    float y0 = bf2f(hs[0]) * d2 + bb[0] + xr[0];
    float y1 = bf2f(hs[1]) * d2 + bb[1] + xr[1];
    float y2 = bf2f(hs[2]) * d2 + bb[2] + xr[2];
    float y3 = bf2f(hs[3]) * d2 + bb[3] + xr[3];
    int e0 = rsL[row], e1 = rsL[row + 1];
    for (int i = e0; i < e1; i++){
      int sc = srcL[i]; float nm = nrmL[i];
      u16x4 hv = *(const u16x4*)&Hs[sc][c0];
      y0 += nm * bf2f(hv[0]);
      y1 += nm * bf2f(hv[1]);
      y2 += nm * bf2f(hv[2]);
      y3 += nm * bf2f(hv[3]);
    }
    float sm = y0 + y1 + y2 + y3;
    float sq = y0*y0 + y1*y1 + y2*y2 + y3*y3;
#pragma unroll
    for (int m = 1; m < 32; m <<= 1){
      sm += __shfl_xor(sm, m, 32);
      sq += __shfl_xor(sq, m, 32);
    }
    float mu   = sm * (1.0f / 128.0f);
    float var  = sq * (1.0f / 128.0f) - mu * mu;
    float rstd = rsqrtf(var + 1e-5f);
    f32x4 g4 = *(const f32x4*)&gbb[0][c0];
    f32x4 b4 = *(const f32x4*)&gbb[1][c0];
    f32x4 o;
    o[0] = fmaxf(0.f, (y0 - mu) * rstd * g4[0] + b4[0]);
    o[1] = fmaxf(0.f, (y1 - mu) * rstd * g4[1] + b4[1]);
    o[2] = fmaxf(0.f, (y2 - mu) * rstd * g4[2] + b4[2]);
    o[3] = fmaxf(0.f, (y3 - mu) * rstd * g4[3] + b4[3]);
    *(f32x4*)(out + gbase) = o;
  }
}

// ---------------- fallback (round-5 kernel, proven) ----------------
__global__ __launch_bounds__(256, 4)
void gcn_fused(const float* __restrict__ x, const int* __restrict__ ei,
               const float* __restrict__ W, const float* __restrict__ bias,
               const float* __restrict__ ew, const float* __restrict__ gamma,
               const float* __restrict__ beta, float* __restrict__ out,
               const u16* __restrict__ wpack, int npairs)
{
  __shared__ alignas(16) u16 Hs[ROWS][LDW];
  __shared__ float gbb[3][CH];
  __shared__ float deg[ROWS];
  __shared__ int   cnt[ROWS], cnt2[ROWS], rs[ROWS + 1];
  __shared__ int   c_src[EDG];
  __shared__ float c_nrm[EDG];

  const int tid  = threadIdx.x;
  const int lane = tid & 63;
  const int wv   = tid >> 6;
  const int hi   = lane >> 4;
  const int p    = blockIdx.x;
  const int Etot = npairs * EDG;

  int es = 0, ed = 0; float eww = 0.f;
  if (tid < EDG){
    es  = ei[p * EDG + tid]        - p * ROWS;
    ed  = ei[Etot + p * EDG + tid] - p * ROWS;
    eww = ew[(tid >= EPG) ? (tid - EPG) : tid];
  }
  if (tid < ROWS){ deg[tid] = 1.0f; cnt[tid] = 0; cnt2[tid] = 0; }
  if (tid < CH){
    gbb[0][tid] = gamma[tid]; gbb[1][tid] = beta[tid]; gbb[2][tid] = bias[tid];
  }

  const int arow = 16 * wv + (lane & 15);
  const int rowc = arow < ROWS ? arow : ROWS - 1;
  const float* xp = x + ((size_t)p * ROWS + rowc) * CH + hi * 8;

  f32x4 acc[8];
  {
    bf16x8 afr[4];
#pragma unroll
    for (int ks = 0; ks < 4; ks++){
      f32x4 lo = *(const f32x4*)(xp + ks * 32);
      f32x4 h4 = *(const f32x4*)(xp + ks * 32 + 4);
      u16x8 t;
      t[0] = f2bf(lo[0]); t[1] = f2bf(lo[1]); t[2] = f2bf(lo[2]); t[3] = f2bf(lo[3]);
      t[4] = f2bf(h4[0]); t[5] = f2bf(h4[1]); t[6] = f2bf(h4[2]); t[7] = f2bf(h4[3]);
      afr[ks] = __builtin_bit_cast(bf16x8, t);
    }
#pragma unroll
    for (int ct = 0; ct < 8; ct++){
      acc[ct] = (f32x4){0.f, 0.f, 0.f, 0.f};
#pragma unroll
      for (int ks = 0; ks < 4; ks++){
        u16x8 b;
        if (wpack){
          b = ((const u16x8*)wpack)[((ct << 2) + ks) * 64 + lane];
        } else {
#pragma unroll
          for (int j = 0; j < 8; j++){
            int k = hi * 8 + ks * 32 + j;
            int c = ct * 16 + (lane & 15);
            b[j] = f2bf(W[k * CH + c]);
          }
        }
        acc[ct] = __builtin_amdgcn_mfma_f32_16x16x32_bf16(
                    afr[ks], __builtin_bit_cast(bf16x8, b), acc[ct], 0, 0, 0);
      }
    }
  }

  {
    int r0 = 16 * wv + (hi << 2);
    int cc = lane & 15;
#pragma unroll
    for (int ct = 0; ct < 8; ct++){
#pragma unroll
      for (int r = 0; r < 4; r++){
        int rr = r0 + r;
        if (rr < ROWS) Hs[rr][16 * ct + cc] = f2bf(acc[ct][r]);
      }
    }
  }
  __syncthreads();

  if (tid < EDG){
    atomicAdd(&deg[ed], eww);
    atomicAdd(&cnt[ed], 1);
  }
  __syncthreads();

  if (tid < ROWS) deg[tid] = rsqrtf(deg[tid]);
  if (wv == 0){
    int v = (lane < ROWS) ? cnt[lane] : 0;
#pragma unroll
    for (int off = 1; off < 64; off <<= 1){
      int n = __shfl_up(v, off, 64);
      if (lane >= off) v += n;
    }
    if (lane < ROWS) rs[lane + 1] = v;
    if (lane == 0)   rs[0] = 0;
  }
  __syncthreads();

  if (tid < EDG){
    float nrm = deg[es] * eww * deg[ed];
    int slot = rs[ed] + atomicAdd(&cnt2[ed], 1);
    c_src[slot] = es;
    c_nrm[slot] = nrm;
  }
  __syncthreads();

  const int half = lane >> 5;
  const int l32  = lane & 31;
  const int c0   = l32 * 4;
  for (int rp = wv; rp < ROWS / 2; rp += 4){
    int row = 2 * rp + half;
    float dv = deg[row];
    float d2 = dv * dv;
    size_t gbase = ((size_t)p * ROWS + row) * CH + c0;
    u16x4 hs = *(const u16x4*)&Hs[row][c0];
    f32x4 xr = *(const f32x4*)(x + gbase);
    f32x4 bb = *(const f32x4*)&gbb[2][c0];
    float y0 = bf2f(hs[0]) * d2 + bb[0] + xr[0];
    float y1 = bf2f(hs[1]) * d2 + bb[1] + xr[1];
    float y2 = bf2f(hs[2]) * d2 + bb[2] + xr[2];
    float y3 = bf2f(hs[3]) * d2 + bb[3] + xr[3];
    int s0 = rs[row], s1 = rs[row + 1];
    for (int i = s0; i < s1; i++){
      int sc = c_src[i]; float nm = c_nrm[i];
      u16x4 hv = *(const u16x4*)&Hs[sc][c0];
      y0 += nm * bf2f(hv[0]);
      y1 += nm * bf2f(hv[1]);
      y2 += nm * bf2f(hv[2]);
      y3 += nm * bf2f(hv[3]);
    }
    float sm = y0 + y1 + y2 + y3;
    float sq = y0*y0 + y1*y1 + y2*y2 + y3*y3;
#pragma unroll
    for (int m = 1; m < 32; m <<= 1){
      sm += __shfl_xor(sm, m, 32);
      sq += __shfl_xor(sq, m, 32);
    }
    float mu   = sm * (1.0f / 128.0f);
    float var  = sq * (1.0f / 128.0f) - mu * mu;
    float rstd = rsqrtf(var + 1e-5f);
    f32x4 g4 = *(const f32x4*)&gbb[0][c0];
    f32x4 b4 = *(const f32x4*)&gbb[1][c0];
    f32x4 o;
    o[0] = fmaxf(0.f, (y0 - mu) * rstd * g4[0] + b4[0]);
    o[1] = fmaxf(0.f, (y1 - mu) * rstd * g4[1] + b4[1]);
    o[2] = fmaxf(0.f, (y2 - mu) * rstd * g4[2] + b4[2]);
    o[3] = fmaxf(0.f, (y3 - mu) * rstd * g4[3] + b4[3]);
    *(f32x4*)(out + gbase) = o;
  }
}

extern "C" void kernel_launch(void* const* d_in, const int* in_sizes, int n_in,
                              void* d_out, int out_size, void* d_ws, size_t ws_size,
                              hipStream_t stream)
{
  const float* x     = (const float*)d_in[0];
  const int*   ei    = (const int*)d_in[1];
  const float* W     = (const float*)d_in[2];
  const float* bias  = (const float*)d_in[3];
  const float* ew    = (const float*)d_in[4];
  const float* gamma = (const float*)d_in[5];
  const float* beta  = (const float*)d_in[6];
  float* out = (float*)d_out;

  int N = in_sizes[0] / CH;          // 458752
  int npairs = N / ROWS;             // 8192

  const size_t wpack_bytes = (size_t)CH * CH * sizeof(u16);       // 32 KB
  const size_t csr_bytes   = (size_t)npairs * CSR_WORDS * 4;      // 12.6 MB

  if (ws_size >= wpack_bytes + csr_bytes){
    u16* wpack = (u16*)d_ws;
    int* csr   = (int*)((char*)d_ws + wpack_bytes);
    hipLaunchKernelGGL(pack_w, dim3(CH * CH / 256), dim3(256), 0, stream, W, wpack);
    hipLaunchKernelGGL(build_csr, dim3(npairs), dim3(128), 0, stream, ei, ew, csr, npairs);
    hipLaunchKernelGGL(gcn_main, dim3(npairs), dim3(256), 0, stream,
                       x, bias, gamma, beta, out, wpack, csr, npairs);
  } else {
    u16* wpack = nullptr;
    if (ws_size >= wpack_bytes){
      wpack = (u16*)d_ws;
      hipLaunchKernelGGL(pack_w, dim3(CH * CH / 256), dim3(256), 0, stream, W, wpack);
    }
    hipLaunchKernelGGL(gcn_fused, dim3(npairs), dim3(256), 0, stream,
                       x, ei, W, bias, ew, gamma, beta, out, wpack, npairs);
  }
}